// Round 3
// baseline (331.796 us; speedup 1.0000x reference)
//
#include <hip/hip_runtime.h>

// BTT(4096->4096, m=n=a=b=64, rank=8) == dense 4096x4096 matmul:
//   W[n*64+b][m*64+a] = sum_r R[n,b,m*8+r] * L[m,n*8+r,a];  out = x @ W + bias
// prep_w (W^T bf16) + prep_x (x bf16) + barrier-free wave-private pipelined GEMM.

typedef float f32x4 __attribute__((ext_vector_type(4)));
typedef short short8 __attribute__((ext_vector_type(8)));

static __device__ __forceinline__ unsigned short f2b(float f) {
    union { float f; unsigned u; } a; a.f = f;
    unsigned u = a.u;
    unsigned r = u + 0x7fffu + ((u >> 16) & 1u);   // RNE
    return (unsigned short)(r >> 16);
}

static __device__ __forceinline__ void load_lds_16(const void* gptr, void* lptr) {
    __builtin_amdgcn_global_load_lds(
        (const __attribute__((address_space(1))) unsigned int*)gptr,
        (__attribute__((address_space(3))) unsigned int*)lptr, 16, 0, 0);
}

#define VMWAIT16 asm volatile("s_waitcnt vmcnt(16)" ::: "memory")
#define VMWAIT0  asm volatile("s_waitcnt vmcnt(0)" ::: "memory")

// ---------------- prep_w ----------------
__global__ __launch_bounds__(256) void prep_w(
    const float* __restrict__ btt_r,   // [64][64][512]
    const float* __restrict__ btt_l,   // [64][512][64]
    unsigned short* __restrict__ Wt)   // [4096][4096] bf16, Wt[ma][nb]
{
    __shared__ float Rs[64][8];
    __shared__ float Ls[8][64];
    const int m = blockIdx.x, n = blockIdx.y, tid = threadIdx.x;

    if (tid < 128) {
        int b = tid >> 1, rh = (tid & 1) * 4;
        float4 v = *(const float4*)(btt_r + (size_t)n * 32768 + (size_t)b * 512 + m * 8 + rh);
        *(float4*)&Rs[b][rh] = v;
    } else {
        int t2 = (tid - 128) * 4;
        float4 v = *(const float4*)(btt_l + (size_t)m * 32768 + n * 512 + t2);
        *(float4*)&(&Ls[0][0])[t2] = v;
    }
    __syncthreads();

    const int a  = tid >> 2;
    const int bg = (tid & 3) * 16;
    float la[8];
    #pragma unroll
    for (int r = 0; r < 8; ++r) la[r] = Ls[r][a];

    unsigned short o[16];
    #pragma unroll
    for (int bb = 0; bb < 16; ++bb) {
        float acc = 0.f;
        #pragma unroll
        for (int r = 0; r < 8; ++r) acc += Rs[bg + bb][r] * la[r];
        o[bb] = f2b(acc);
    }
    size_t off = (size_t)(m * 64 + a) * 4096 + n * 64 + bg;
    *(uint4*)&Wt[off]     = *(const uint4*)&o[0];
    *(uint4*)&Wt[off + 8] = *(const uint4*)&o[8];
}

// ---------------- prep_x ----------------
__global__ __launch_bounds__(256) void prep_x(
    const float* __restrict__ x, unsigned short* __restrict__ xb, int total8)
{
    int i = blockIdx.x * 256 + threadIdx.x;
    if (i >= total8) return;
    size_t off = (size_t)i * 8;
    float4 v0 = *(const float4*)(x + off);
    float4 v1 = *(const float4*)(x + off + 4);
    unsigned short o[8];
    o[0] = f2b(v0.x); o[1] = f2b(v0.y); o[2] = f2b(v0.z); o[3] = f2b(v0.w);
    o[4] = f2b(v1.x); o[5] = f2b(v1.y); o[6] = f2b(v1.z); o[7] = f2b(v1.w);
    *(uint4*)(xb + off) = *(const uint4*)o;
}

// ---------------- gemm: barrier-free wave-private pipeline ----------------
// 1 wave/block, 64x64 tile, BK=64, dbuf LDS (A0/A1/B0/B1), XOR-swizzled granules.
// grid: 4096 blocks (swizzled 64x64 tiles), block: 64
__global__ __launch_bounds__(64) void gemm_btt(
    const unsigned short* __restrict__ xb,   // [4096][4096] bf16 rows
    const unsigned short* __restrict__ Wt,   // [4096][4096] bf16 [col][k]
    const float* __restrict__ bias,
    float* __restrict__ out)
{
    __shared__ unsigned short A0[64 * 64];
    __shared__ unsigned short A1[64 * 64];
    __shared__ unsigned short B0[64 * 64];
    __shared__ unsigned short B1[64 * 64];

    const int tid = threadIdx.x;             // one wave
    // 8x8 super-tile swizzle for L2 locality
    const int gid  = blockIdx.x;
    const int sgid = gid >> 6;
    const int st   = gid & 63;
    const int rt = (sgid >> 3) * 8 + (st >> 3);
    const int ct = (sgid & 7) * 8 + (st & 7);
    const int rowbase = rt * 64;
    const int colbase = ct * 64;

    const int lane = tid & 63;
    const int quad = lane >> 4;
    const int lr   = lane & 15;

    const unsigned short* xa = xb + (size_t)rowbase * 4096;
    const unsigned short* wa = Wt + (size_t)colbase * 4096;

    f32x4 acc[4][4];
    #pragma unroll
    for (int i = 0; i < 4; ++i)
        #pragma unroll
        for (int j = 0; j < 4; ++j)
            acc[i][j] = (f32x4){0.f, 0.f, 0.f, 0.f};

#define STAGE(Ab, Bb, kt) do {                                                   \
    _Pragma("unroll")                                                            \
    for (int p = 0; p < 8; ++p) {                                                \
        int o = p * 64 + tid;                                                    \
        int row = o >> 3;                                                        \
        int sgr = (o & 7) ^ (row & 7);                                           \
        load_lds_16(xa + (size_t)row * 4096 + (kt) * 64 + sgr * 8, &Ab[o * 8]);  \
        load_lds_16(wa + (size_t)row * 4096 + (kt) * 64 + sgr * 8, &Bb[o * 8]);  \
    } } while (0)

#define COMPUTE(Ab, Bb) do {                                                     \
    _Pragma("unroll")                                                            \
    for (int kk = 0; kk < 2; ++kk) {                                             \
        const int kg = kk * 4 + quad;                                            \
        const int gx = (kg ^ (lr & 7)) * 8;                                      \
        short8 af[4], bf[4];                                                     \
        _Pragma("unroll")                                                        \
        for (int i = 0; i < 4; ++i)                                              \
            af[i] = *(const short8*)&Ab[(i * 16 + lr) * 64 + gx];                \
        _Pragma("unroll")                                                        \
        for (int j = 0; j < 4; ++j)                                              \
            bf[j] = *(const short8*)&Bb[(j * 16 + lr) * 64 + gx];                \
        _Pragma("unroll")                                                        \
        for (int i = 0; i < 4; ++i)                                              \
            _Pragma("unroll")                                                    \
            for (int j = 0; j < 4; ++j)                                          \
                acc[i][j] = __builtin_amdgcn_mfma_f32_16x16x32_bf16(             \
                    af[i], bf[j], acc[i][j], 0, 0, 0);                           \
    } } while (0)

    STAGE(A0, B0, 0);
    STAGE(A1, B1, 1);
    for (int p2 = 0; p2 < 31; ++p2) {
        VMWAIT16;
        COMPUTE(A0, B0);
        STAGE(A0, B0, 2 * p2 + 2);
        VMWAIT16;
        COMPUTE(A1, B1);
        STAGE(A1, B1, 2 * p2 + 3);
    }
    VMWAIT16;
    COMPUTE(A0, B0);
    VMWAIT0;
    COMPUTE(A1, B1);

#undef STAGE
#undef COMPUTE

    // epilogue: fp32 + bias
    #pragma unroll
    for (int j = 0; j < 4; ++j) {
        const int col = colbase + j * 16 + lr;
        const float bv = bias[col];
        #pragma unroll
        for (int i = 0; i < 4; ++i) {
            const int row = rowbase + i * 16 + quad * 4;
            #pragma unroll
            for (int t = 0; t < 4; ++t)
                out[(size_t)(row + t) * 4096 + col] = acc[i][j][t] + bv;
        }
    }
}

extern "C" void kernel_launch(void* const* d_in, const int* in_sizes, int n_in,
                              void* d_out, int out_size, void* d_ws, size_t ws_size,
                              hipStream_t stream) {
    const float* x    = (const float*)d_in[0];
    const float* r    = (const float*)d_in[1];
    const float* l    = (const float*)d_in[2];
    const float* bias = (const float*)d_in[3];
    float* out = (float*)d_out;

    unsigned short* xb = (unsigned short*)d_ws;                       // 32 MB
    unsigned short* Wt = (unsigned short*)d_ws + (size_t)4096 * 4096; // 32 MB

    const int rows = in_sizes[0] / 4096;   // 4096
    const int total8 = rows * 4096 / 8;

    prep_w<<<dim3(64, 64), dim3(256), 0, stream>>>(r, l, Wt);
    prep_x<<<dim3(total8 / 256), dim3(256), 0, stream>>>(x, xb, total8);
    gemm_btt<<<dim3((rows / 64) * 64), dim3(64), 0, stream>>>(xb, Wt, bias, out);
}

// Round 4
// 296.866 us; speedup vs baseline: 1.1177x; 1.1177x over previous
//
#include <hip/hip_runtime.h>

// BTT(4096->4096, m=n=a=b=64, rank=8) == dense 4096x4096 matmul:
//   W[n*64+b][m*64+a] = sum_r R[n,b,m*8+r] * L[m,n*8+r,a];  out = x @ W + bias
// Pipeline: merged prep (W^T bf16 + x bf16) + 128x128 4-wave GEMM w/ 32x32x16 MFMA.

typedef float f32x16 __attribute__((ext_vector_type(16)));
typedef short short8 __attribute__((ext_vector_type(8)));

static __device__ __forceinline__ unsigned short f2b(float f) {
    union { float f; unsigned u; } a; a.f = f;
    unsigned u = a.u;
    unsigned r = u + 0x7fffu + ((u >> 16) & 1u);   // RNE
    return (unsigned short)(r >> 16);
}

static __device__ __forceinline__ void load_lds_16(const void* gptr, void* lptr) {
    __builtin_amdgcn_global_load_lds(
        (const __attribute__((address_space(1))) unsigned int*)gptr,
        (__attribute__((address_space(3))) unsigned int*)lptr, 16, 0, 0);
}

// ---------------- merged prep: blocks [0, nx) do x->bf16, blocks [nx, nx+4096) do W ----
__global__ __launch_bounds__(256) void prep_all(
    const float* __restrict__ x,       // [rows][4096]
    const float* __restrict__ btt_r,   // [64][64][512]
    const float* __restrict__ btt_l,   // [64][512][64]
    unsigned short* __restrict__ xb,   // [rows][4096] bf16
    unsigned short* __restrict__ Wt,   // [4096][4096] bf16, Wt[ma][nb]
    int nx)
{
    const int tid = threadIdx.x;
    if ((int)blockIdx.x < nx) {
        // ---- x conversion: 8 elems/thread
        size_t i = (size_t)blockIdx.x * 256 + tid;
        size_t off = i * 8;
        float4 v0 = *(const float4*)(x + off);
        float4 v1 = *(const float4*)(x + off + 4);
        unsigned short o[8];
        o[0] = f2b(v0.x); o[1] = f2b(v0.y); o[2] = f2b(v0.z); o[3] = f2b(v0.w);
        o[4] = f2b(v1.x); o[5] = f2b(v1.y); o[6] = f2b(v1.z); o[7] = f2b(v1.w);
        *(uint4*)(xb + off) = *(const uint4*)o;
        return;
    }
    // ---- W composition
    __shared__ float Rs[64][8];
    __shared__ float Ls[8][64];
    const int wb = blockIdx.x - nx;
    const int m = wb >> 6, n = wb & 63;

    if (tid < 128) {
        int b = tid >> 1, rh = (tid & 1) * 4;
        float4 v = *(const float4*)(btt_r + (size_t)n * 32768 + (size_t)b * 512 + m * 8 + rh);
        *(float4*)&Rs[b][rh] = v;
    } else {
        int t2 = (tid - 128) * 4;
        float4 v = *(const float4*)(btt_l + (size_t)m * 32768 + n * 512 + t2);
        *(float4*)&(&Ls[0][0])[t2] = v;
    }
    __syncthreads();

    const int a  = tid >> 2;
    const int bg = (tid & 3) * 16;
    float la[8];
    #pragma unroll
    for (int r = 0; r < 8; ++r) la[r] = Ls[r][a];

    unsigned short o[16];
    #pragma unroll
    for (int bb = 0; bb < 16; ++bb) {
        float acc = 0.f;
        #pragma unroll
        for (int r = 0; r < 8; ++r) acc += Rs[bg + bb][r] * la[r];
        o[bb] = f2b(acc);
    }
    size_t off = (size_t)(m * 64 + a) * 4096 + n * 64 + bg;
    *(uint4*)&Wt[off]     = *(const uint4*)&o[0];
    *(uint4*)&Wt[off + 8] = *(const uint4*)&o[8];
}

// ---------------- gemm: 128x128 tile, BK=64, 4 waves, 32x32x16 MFMA ----------------
// grid (32 colTiles, 32 rowTiles), block 256; XOR-swizzled LDS granules.
__global__ __launch_bounds__(256) void gemm_btt(
    const unsigned short* __restrict__ xb,   // [4096][4096] bf16 rows
    const unsigned short* __restrict__ Wt,   // [4096][4096] bf16 [col][k]
    const float* __restrict__ bias,
    float* __restrict__ out)
{
    __shared__ unsigned short As[128 * 64];  // [row][granule g], slot g holds src granule g^(row&7)
    __shared__ unsigned short Bs[128 * 64];

    const int tid = threadIdx.x;
    const int colbase = blockIdx.x * 128;
    const int rowbase = blockIdx.y * 128;

    const int wid  = tid >> 6;
    const int lane = tid & 63;
    const int half = lane >> 5;
    const int l31  = lane & 31;
    const int wrow = (wid >> 1) * 64;
    const int wcol = (wid & 1) * 64;

    f32x16 acc[2][2];
    #pragma unroll
    for (int i = 0; i < 2; ++i)
        #pragma unroll
        for (int j = 0; j < 2; ++j)
            #pragma unroll
            for (int r = 0; r < 16; ++r)
                acc[i][j][r] = 0.f;

    for (int it = 0; it < 64; ++it) {
        const int k0 = it * 64;
        #pragma unroll
        for (int p = 0; p < 4; ++p) {
            int o = p * 256 + tid;
            int row = o >> 3;
            int sgr = (o & 7) ^ (row & 7);     // source granule for this slot
            load_lds_16(xb + (size_t)(rowbase + row) * 4096 + k0 + sgr * 8, &As[o * 8]);
            load_lds_16(Wt + (size_t)(colbase + row) * 4096 + k0 + sgr * 8, &Bs[o * 8]);
        }
        __syncthreads();

        #pragma unroll
        for (int ks = 0; ks < 4; ++ks) {
            const int c = ks * 2 + half;       // logical granule (k = c*8 + j)
            short8 af[2], bf[2];
            #pragma unroll
            for (int i = 0; i < 2; ++i) {
                int row = wrow + i * 32 + l31;
                af[i] = *(const short8*)&As[row * 64 + ((c ^ (row & 7)) * 8)];
            }
            #pragma unroll
            for (int j = 0; j < 2; ++j) {
                int row = wcol + j * 32 + l31;
                bf[j] = *(const short8*)&Bs[row * 64 + ((c ^ (row & 7)) * 8)];
            }
            #pragma unroll
            for (int i = 0; i < 2; ++i)
                #pragma unroll
                for (int j = 0; j < 2; ++j)
                    acc[i][j] = __builtin_amdgcn_mfma_f32_32x32x16_bf16(
                        af[i], bf[j], acc[i][j], 0, 0, 0);
        }
        __syncthreads();
    }

    // epilogue: C/D layout col=lane&31, row=(r&3)+8*(r>>2)+4*half  [m74/m101 verified]
    #pragma unroll
    for (int j = 0; j < 2; ++j) {
        const int col = colbase + wcol + j * 32 + l31;
        const float bv = bias[col];
        #pragma unroll
        for (int i = 0; i < 2; ++i) {
            const int rbase = rowbase + wrow + i * 32 + 4 * half;
            #pragma unroll
            for (int r = 0; r < 16; ++r) {
                int row = rbase + (r & 3) + 8 * (r >> 2);
                out[(size_t)row * 4096 + col] = acc[i][j][r] + bv;
            }
        }
    }
}

extern "C" void kernel_launch(void* const* d_in, const int* in_sizes, int n_in,
                              void* d_out, int out_size, void* d_ws, size_t ws_size,
                              hipStream_t stream) {
    const float* x    = (const float*)d_in[0];
    const float* r    = (const float*)d_in[1];
    const float* l    = (const float*)d_in[2];
    const float* bias = (const float*)d_in[3];
    float* out = (float*)d_out;

    unsigned short* xb = (unsigned short*)d_ws;                       // 32 MB
    unsigned short* Wt = (unsigned short*)d_ws + (size_t)4096 * 4096; // 32 MB

    const int rows = in_sizes[0] / 4096;        // 4096
    const int nx = rows * 4096 / 8 / 256;       // 8192 x-conversion blocks

    prep_all<<<dim3(nx + 4096), dim3(256), 0, stream>>>(x, r, l, xb, Wt, nx);
    gemm_btt<<<dim3(32, rows / 128), dim3(256), 0, stream>>>(xb, Wt, bias, out);
}

// Round 5
// 290.771 us; speedup vs baseline: 1.1411x; 1.0210x over previous
//
#include <hip/hip_runtime.h>

// BTT(4096->4096, m=n=a=b=64, rank=8) == dense 4096x4096 matmul:
//   W[n*64+b][m*64+a] = sum_r R[n,b,m*8+r] * L[m,n*8+r,a];  out = x @ W + bias
// R5: xb/Wt stored FRAGMENT-MAJOR ([tile128][ktile64][frag16][lane64][8] bf16) so
// gemm staging is linear 16KB DMA and ds_read_b128 is conflict-free by construction.

typedef float f32x16 __attribute__((ext_vector_type(16)));
typedef short short8 __attribute__((ext_vector_type(8)));

static __device__ __forceinline__ unsigned short f2b(float f) {
    union { float f; unsigned u; } a; a.f = f;
    unsigned u = a.u;
    unsigned r = u + 0x7fffu + ((u >> 16) & 1u);   // RNE
    return (unsigned short)(r >> 16);
}

static __device__ __forceinline__ void load_lds_16(const void* gptr, void* lptr) {
    __builtin_amdgcn_global_load_lds(
        (const __attribute__((address_space(1))) unsigned int*)gptr,
        (__attribute__((address_space(3))) unsigned int*)lptr, 16, 0, 0);
}

// ---------------- merged prep: blocks [0,nx) convert x, blocks [nx,nx+4096) build W ----
// Fragment-major dst: elem (row,k) -> tile=row>>7, it=k>>6, frag=((row>>5)&3)*4+((k>>4)&3),
//                     lane=((k>>3)&1)*32+(row&31), j=k&7
__global__ __launch_bounds__(256) void prep_all(
    const float* __restrict__ x,       // [4096][4096]
    const float* __restrict__ btt_r,   // [64][64][512]
    const float* __restrict__ btt_l,   // [64][512][64]
    unsigned short* __restrict__ xbt,  // tiled bf16
    unsigned short* __restrict__ Wtt,  // tiled bf16
    int nx)
{
    const int tid = threadIdx.x;
    if ((int)blockIdx.x < nx) {
        // ---- x conversion: 1 granule (8 elems) / thread; 8-row thread groups so
        // tiled writes coalesce into 128B lines.
        unsigned i = blockIdx.x * 256 + tid;
        int row = ((i >> 12) << 3) | (i & 7);
        int g   = (i >> 3) & 511;          // k-granule 0..511
        float4 v0 = *(const float4*)(x + (size_t)row * 4096 + g * 8);
        float4 v1 = *(const float4*)(x + (size_t)row * 4096 + g * 8 + 4);
        unsigned short o[8];
        o[0] = f2b(v0.x); o[1] = f2b(v0.y); o[2] = f2b(v0.z); o[3] = f2b(v0.w);
        o[4] = f2b(v1.x); o[5] = f2b(v1.y); o[6] = f2b(v1.z); o[7] = f2b(v1.w);
        int it = g >> 3, q = g & 7;
        int ks = q >> 1, half = q & 1;
        int rt = row >> 7, a2 = (row >> 5) & 3, l31 = row & 31;
        size_t dst = (((size_t)(rt * 64 + it) * 16 + a2 * 4 + ks) * 64 + half * 32 + l31) * 8;
        *(uint4*)(xbt + dst) = *(const uint4*)o;
        return;
    }
    // ---- W composition (per (m,n) block), tiled dst
    __shared__ float Rs[64][8];
    __shared__ float Ls[8][64];
    const int wb = blockIdx.x - nx;
    const int m = wb >> 6, n = wb & 63;

    if (tid < 128) {
        int b = tid >> 1, rh = (tid & 1) * 4;
        float4 v = *(const float4*)(btt_r + (size_t)n * 32768 + (size_t)b * 512 + m * 8 + rh);
        *(float4*)&Rs[b][rh] = v;
    } else {
        int t2 = (tid - 128) * 4;
        float4 v = *(const float4*)(btt_l + (size_t)m * 32768 + n * 512 + t2);
        *(float4*)&(&Ls[0][0])[t2] = v;
    }
    __syncthreads();

    const int a  = tid >> 2;
    const int bg = (tid & 3) * 16;     // k-offset within n-block: 0,16,32,48
    float la[8];
    #pragma unroll
    for (int r = 0; r < 8; ++r) la[r] = Ls[r][a];

    unsigned short o[16];
    #pragma unroll
    for (int bb = 0; bb < 16; ++bb) {
        float acc = 0.f;
        #pragma unroll
        for (int r = 0; r < 8; ++r) acc += Rs[bg + bb][r] * la[r];
        o[bb] = f2b(acc);
    }
    // col = m*64+a (gemm "row" of W^T); k = n*64 + bg + t
    int col = m * 64 + a;
    int ct = col >> 7, b2 = (col >> 5) & 3, l31 = col & 31;
    int ks = bg >> 4;
    size_t dst = (((size_t)(ct * 64 + n) * 16 + b2 * 4 + ks) * 64 + l31) * 8;
    *(uint4*)(Wtt + dst)           = *(const uint4*)&o[0];   // half 0
    *(uint4*)(Wtt + dst + 32 * 8)  = *(const uint4*)&o[8];   // half 1
}

// ---------------- gemm: 128x128 tile, BK=64, 4 waves, 32x32x16 MFMA ----------------
// Fragment-major LDS: As/Bs = [frag16][lane64][8]; staging = linear 16KB DMA.
__global__ __launch_bounds__(256) void gemm_btt(
    const unsigned short* __restrict__ xbt,  // tiled
    const unsigned short* __restrict__ Wtt,  // tiled
    const float* __restrict__ bias,
    float* __restrict__ out)
{
    __shared__ unsigned short As[16 * 512];  // 16KB
    __shared__ unsigned short Bs[16 * 512];

    const int tid = threadIdx.x;
    const int ct = blockIdx.x;
    const int rt = blockIdx.y;

    const int wid  = tid >> 6;
    const int l    = tid & 63;
    const int half = l >> 5;
    const int l31  = l & 31;
    const int i2base = (wid >> 1) * 2;       // A frag row-block base
    const int j2base = (wid & 1) * 2;        // B frag col-block base

    const unsigned short* xa = xbt + (size_t)rt * 524288;   // 64 it * 8192
    const unsigned short* wa = Wtt + (size_t)ct * 524288;

    f32x16 acc[2][2];
    #pragma unroll
    for (int i = 0; i < 2; ++i)
        #pragma unroll
        for (int j = 0; j < 2; ++j)
            #pragma unroll
            for (int r = 0; r < 16; ++r)
                acc[i][j][r] = 0.f;

    for (int it = 0; it < 64; ++it) {
        const size_t kb = (size_t)it * 8192;
        #pragma unroll
        for (int p = 0; p < 4; ++p) {
            int o = p * 256 + tid;
            load_lds_16(xa + kb + o * 8, &As[o * 8]);
            load_lds_16(wa + kb + o * 8, &Bs[o * 8]);
        }
        __syncthreads();

        #pragma unroll
        for (int ks = 0; ks < 4; ++ks) {
            short8 af[2], bf[2];
            #pragma unroll
            for (int i = 0; i < 2; ++i)
                af[i] = *(const short8*)&As[((i2base + i) * 4 + ks) * 512 + l * 8];
            #pragma unroll
            for (int j = 0; j < 2; ++j)
                bf[j] = *(const short8*)&Bs[((j2base + j) * 4 + ks) * 512 + l * 8];
            #pragma unroll
            for (int i = 0; i < 2; ++i)
                #pragma unroll
                for (int j = 0; j < 2; ++j)
                    acc[i][j] = __builtin_amdgcn_mfma_f32_32x32x16_bf16(
                        af[i], bf[j], acc[i][j], 0, 0, 0);
        }
        __syncthreads();
    }

    // epilogue: C/D layout col=lane&31, row=(r&3)+8*(r>>2)+4*half  [m74/m101]
    const int rowTileBase = rt * 128 + (wid >> 1) * 64;
    const int colTileBase = ct * 128 + (wid & 1) * 64;
    #pragma unroll
    for (int j = 0; j < 2; ++j) {
        const int col = colTileBase + j * 32 + l31;
        const float bv = bias[col];
        #pragma unroll
        for (int i = 0; i < 2; ++i) {
            const int rbase = rowTileBase + i * 32 + 4 * half;
            #pragma unroll
            for (int r = 0; r < 16; ++r) {
                int row = rbase + (r & 3) + 8 * (r >> 2);
                out[(size_t)row * 4096 + col] = acc[i][j][r] + bv;
            }
        }
    }
}

extern "C" void kernel_launch(void* const* d_in, const int* in_sizes, int n_in,
                              void* d_out, int out_size, void* d_ws, size_t ws_size,
                              hipStream_t stream) {
    const float* x    = (const float*)d_in[0];
    const float* r    = (const float*)d_in[1];
    const float* l    = (const float*)d_in[2];
    const float* bias = (const float*)d_in[3];
    float* out = (float*)d_out;

    unsigned short* xbt = (unsigned short*)d_ws;                       // 32 MB
    unsigned short* Wtt = (unsigned short*)d_ws + (size_t)4096 * 4096; // 32 MB

    const int rows = in_sizes[0] / 4096;        // 4096
    const int nx = rows * 4096 / 8 / 256;       // 8192 x-conversion blocks

    prep_all<<<dim3(nx + 4096), dim3(256), 0, stream>>>(x, r, l, xbt, Wtt, nx);
    gemm_btt<<<dim3(32, rows / 128), dim3(256), 0, stream>>>(xbt, Wtt, bias, out);
}